// Round 1
// baseline (115.488 us; speedup 1.0000x reference)
//
#include <hip/hip_runtime.h>

#define BB 384
#define DD 256
#define MARGIN 0.2f

// ---------------------------------------------------------------------------
// Kernel 1: pairwise squared distances, one block per anchor row.
// Also zeroes the num/den accumulators (workspace is poisoned each call).
// ---------------------------------------------------------------------------
__global__ __launch_bounds__(256) void dist_kernel(const float* __restrict__ x,
                                                   float* __restrict__ dist2,
                                                   double* __restrict__ acc) {
    __shared__ float4 s_xa[DD / 4];
    const int a = blockIdx.x;
    const int tid = threadIdx.x;

    if (a == 0 && tid == 0) { acc[0] = 0.0; acc[1] = 0.0; }

    const float4* x4 = reinterpret_cast<const float4*>(x);
    if (tid < DD / 4) s_xa[tid] = x4[a * (DD / 4) + tid];
    __syncthreads();

    for (int b = tid; b < BB; b += 256) {
        const float4* xb = x4 + b * (DD / 4);
        // 4 independent accumulators (one per float4 lane) to reduce
        // sequential-sum rounding drift vs the fp32 reference.
        float sx = 0.f, sy = 0.f, sz = 0.f, sw = 0.f;
#pragma unroll 8
        for (int d = 0; d < DD / 4; ++d) {
            float4 va = s_xa[d];
            float4 vb = xb[d];
            float dx = va.x - vb.x;
            float dy = va.y - vb.y;
            float dz = va.z - vb.z;
            float dw = va.w - vb.w;
            sx += dx * dx;
            sy += dy * dy;
            sz += dz * dz;
            sw += dw * dw;
        }
        dist2[a * BB + b] = (sx + sy) + (sz + sw);
    }
}

// ---------------------------------------------------------------------------
// Kernel 2: per-anchor triplet accumulation.
//   num += counts[a] * sum_{p>a,same} sum_{n,diff} relu(margin + d_ap - d_an)
//   den += counts[a] * npos(a) * (B - counts[a])
// ---------------------------------------------------------------------------
__global__ __launch_bounds__(256) void triplet_kernel(const float* __restrict__ dist2,
                                                      const int* __restrict__ labels,
                                                      double* __restrict__ acc) {
    __shared__ int s_lab[BB];
    __shared__ float s_d[BB];
    __shared__ double s_red[4];

    const int a = blockIdx.x;
    const int tid = threadIdx.x;

    for (int i = tid; i < BB; i += 256) {
        s_lab[i] = labels[i];
        s_d[i] = dist2[a * BB + i];
    }
    __syncthreads();

    const int la = s_lab[a];

    // Every thread scans all labels from LDS (same-address broadcast: free).
    int cnt = 0, npos = 0;
    for (int b = 0; b < BB; ++b) {
        int m = (s_lab[b] == la) ? 1 : 0;
        cnt += m;
        if (b > a) npos += m;
    }

    double num_local = 0.0;
    for (int p = a + 1; p < BB; ++p) {
        if (s_lab[p] != la) continue;
        const float t = MARGIN + s_d[p];
        for (int n = tid; n < BB; n += 256) {
            if (s_lab[n] == la) continue;
            float l = t - s_d[n];
            if (l > 0.f) num_local += (double)l;
        }
    }

    // Wave-64 shuffle reduce, then cross-wave via LDS.
    for (int off = 32; off > 0; off >>= 1)
        num_local += __shfl_down(num_local, off, 64);
    const int lane = tid & 63, wid = tid >> 6;
    if (lane == 0) s_red[wid] = num_local;
    __syncthreads();

    if (tid == 0) {
        double tot = (s_red[0] + s_red[1]) + (s_red[2] + s_red[3]);
        atomicAdd(&acc[0], tot * (double)cnt);
        atomicAdd(&acc[1], (double)cnt * (double)npos * (double)(BB - cnt));
    }
}

// ---------------------------------------------------------------------------
// Kernel 3: final divide.
// ---------------------------------------------------------------------------
__global__ void finalize_kernel(const double* __restrict__ acc,
                                float* __restrict__ out) {
    double num = acc[0], den = acc[1];
    out[0] = (den > 0.0) ? (float)(num / den) : 0.0f;
}

extern "C" void kernel_launch(void* const* d_in, const int* in_sizes, int n_in,
                              void* d_out, int out_size, void* d_ws, size_t ws_size,
                              hipStream_t stream) {
    const float* x = (const float*)d_in[0];
    const int* labels = (const int*)d_in[1];
    float* out = (float*)d_out;

    // Workspace layout: dist2 (384*384 floats = 589824 B, 8B-aligned), then 2 doubles.
    float* dist2 = (float*)d_ws;
    double* acc = (double*)((char*)d_ws + (size_t)BB * BB * sizeof(float));

    dist_kernel<<<BB, 256, 0, stream>>>(x, dist2, acc);
    triplet_kernel<<<BB, 256, 0, stream>>>(dist2, labels, acc);
    finalize_kernel<<<1, 1, 0, stream>>>(acc, out);
}

// Round 2
// 84.627 us; speedup vs baseline: 1.3647x; 1.3647x over previous
//
#include <hip/hip_runtime.h>

#define BB 384
#define DD 256
#define MARGIN 0.2f

// ---------------------------------------------------------------------------
// Fused kernel: one block per anchor `a`.
//   1. stage x[a] + labels in LDS
//   2. compute dist2 row d(a, b) for all b (row-per-thread, x is L2-resident)
//   3. build explicit positive list {p : p > a, label[p]==label[a]} via LDS
//      atomics (no serial 384-scan with dependent branches)
//   4. sum relu(margin + d_ap - d_an) over positives x negatives
//   5. write per-anchor partial num/den to unique ws slots (no global atomics,
//      no accumulator init race vs the 0xAA poison)
// ---------------------------------------------------------------------------
__global__ __launch_bounds__(256) void triplet_fused_kernel(
    const float* __restrict__ x,
    const int* __restrict__ labels,
    double* __restrict__ partial_num,
    double* __restrict__ partial_den) {
    __shared__ float4 s_xa4[DD / 4];   // anchor row, 1 KB
    __shared__ float  s_d[BB];         // dist2 row, 1.5 KB
    __shared__ int    s_lab[BB];       // labels, 1.5 KB
    __shared__ int    s_pos[BB];       // positive indices (worst case all-same-class)
    __shared__ int    s_np, s_cnt;
    __shared__ double s_red[4];

    const int a = blockIdx.x;
    const int tid = threadIdx.x;
    const float4* x4 = reinterpret_cast<const float4*>(x);

    for (int i = tid; i < BB; i += 256) s_lab[i] = labels[i];
    if (tid < DD / 4) s_xa4[tid] = x4[a * (DD / 4) + tid];
    if (tid == 0) { s_np = 0; s_cnt = 0; }
    __syncthreads();

    const int la = s_lab[a];

    // ---- dist row: thread handles b = tid (+256). Rows stream from L2. ----
    for (int b = tid; b < BB; b += 256) {
        const float4* xb = x4 + b * (DD / 4);
        float sx = 0.f, sy = 0.f, sz = 0.f, sw = 0.f;
#pragma unroll 8
        for (int d = 0; d < DD / 4; ++d) {
            float4 va = s_xa4[d];
            float4 vb = xb[d];
            float dx = va.x - vb.x;
            float dy = va.y - vb.y;
            float dz = va.z - vb.z;
            float dw = va.w - vb.w;
            sx += dx * dx;
            sy += dy * dy;
            sz += dz * dz;
            sw += dw * dw;
        }
        s_d[b] = (sx + sy) + (sz + sw);
    }

    // ---- class count + positive list (parallel, order-independent) ----
    for (int i = tid; i < BB; i += 256) {
        if (s_lab[i] == la) {
            atomicAdd(&s_cnt, 1);
            if (i > a) {
                int k = atomicAdd(&s_np, 1);
                s_pos[k] = i;
            }
        }
    }
    __syncthreads();

    const int np = s_np;
    const int cnt = s_cnt;

    // ---- triplet sum: only real positives (~6) x negatives (384/256) ----
    double num_local = 0.0;
    for (int pi = 0; pi < np; ++pi) {
        const float t = MARGIN + s_d[s_pos[pi]];
        for (int n = tid; n < BB; n += 256) {
            if (s_lab[n] != la) {
                float l = t - s_d[n];
                if (l > 0.f) num_local += (double)l;
            }
        }
    }

    // ---- block reduce (wave-64 shuffle, then LDS across 4 waves) ----
    for (int off = 32; off > 0; off >>= 1)
        num_local += __shfl_down(num_local, off, 64);
    const int lane = tid & 63, wid = tid >> 6;
    if (lane == 0) s_red[wid] = num_local;
    __syncthreads();

    if (tid == 0) {
        double tot = (s_red[0] + s_red[1]) + (s_red[2] + s_red[3]);
        partial_num[a] = tot * (double)cnt;
        partial_den[a] = (double)cnt * (double)np * (double)(BB - cnt);
    }
}

// ---------------------------------------------------------------------------
// Finalize: reduce 384 partial num/den pairs, emit num/den.
// ---------------------------------------------------------------------------
__global__ __launch_bounds__(256) void finalize_kernel(
    const double* __restrict__ partial_num,
    const double* __restrict__ partial_den,
    float* __restrict__ out) {
    __shared__ double s_red[8];
    const int tid = threadIdx.x;

    double n_local = 0.0, d_local = 0.0;
    for (int i = tid; i < BB; i += 256) {
        n_local += partial_num[i];
        d_local += partial_den[i];
    }
    for (int off = 32; off > 0; off >>= 1) {
        n_local += __shfl_down(n_local, off, 64);
        d_local += __shfl_down(d_local, off, 64);
    }
    const int lane = tid & 63, wid = tid >> 6;
    if (lane == 0) { s_red[wid] = n_local; s_red[4 + wid] = d_local; }
    __syncthreads();

    if (tid == 0) {
        double num = (s_red[0] + s_red[1]) + (s_red[2] + s_red[3]);
        double den = (s_red[4] + s_red[5]) + (s_red[6] + s_red[7]);
        out[0] = (den > 0.0) ? (float)(num / den) : 0.0f;
    }
}

extern "C" void kernel_launch(void* const* d_in, const int* in_sizes, int n_in,
                              void* d_out, int out_size, void* d_ws, size_t ws_size,
                              hipStream_t stream) {
    const float* x = (const float*)d_in[0];
    const int* labels = (const int*)d_in[1];
    float* out = (float*)d_out;

    // Workspace: 384 partial nums + 384 partial dens (doubles, 6 KB total).
    double* partial_num = (double*)d_ws;
    double* partial_den = partial_num + BB;

    triplet_fused_kernel<<<BB, 256, 0, stream>>>(x, labels, partial_num, partial_den);
    finalize_kernel<<<1, 256, 0, stream>>>(partial_num, partial_den, out);
}

// Round 3
// 80.276 us; speedup vs baseline: 1.4386x; 1.0542x over previous
//
#include <hip/hip_runtime.h>

#define BB 384
#define DD 256           // floats per row; 64 float4
#define F4 (DD / 4)      // 64
#define APB 2            // anchors per block
#define NBLK (BB / APB)  // 192 blocks
#define MARGIN 0.2f

// ---------------------------------------------------------------------------
// Fused kernel: one block per APB anchors.
// Dist phase: segment-coalesced loads — lane = 16*rr + dd; one instruction
// reads float4 f=16k+dd of rows b0+rr (4 contiguous 256B segments, 16 full
// 64B lines). Anchor fragments in registers; 16-lane shfl_xor butterfly
// reduces each row's diff^2 partials.
// Triplet phase: per-anchor positive list via LDS atomics, then
// positives x negatives relu sum in double.
// ---------------------------------------------------------------------------
__global__ __launch_bounds__(256) void triplet_fused_kernel(
    const float* __restrict__ x,
    const int* __restrict__ labels,
    double* __restrict__ partial_num,
    double* __restrict__ partial_den) {
    __shared__ int    s_lab[BB];
    __shared__ float  s_d[APB][BB];
    __shared__ int    s_pos[BB];
    __shared__ int    s_np, s_cnt;
    __shared__ double s_red[4];

    const int tid  = threadIdx.x;
    const int wave = tid >> 6;
    const int lane = tid & 63;
    const int rr   = lane >> 4;   // row-within-quad: 0..3
    const int dd   = lane & 15;   // dim-segment lane: 0..15
    const int a0   = blockIdx.x * APB;

    const float4* x4 = reinterpret_cast<const float4*>(x);

    for (int i = tid; i < BB; i += 256) s_lab[i] = labels[i];

    // Anchor fragments in registers: xa[j][k] = float4 f = 16k + dd of row a0+j.
    float4 xa[APB][4];
#pragma unroll
    for (int j = 0; j < APB; ++j)
#pragma unroll
        for (int k = 0; k < 4; ++k)
            xa[j][k] = x4[(a0 + j) * F4 + k * 16 + dd];

    // ---- dist rows: each wave covers 96 rows, 4 rows per iteration ----
    for (int b0 = wave * 96; b0 < wave * 96 + 96; b0 += 4) {
        const int b = b0 + rr;
        float4 row[4];
#pragma unroll
        for (int k = 0; k < 4; ++k)
            row[k] = x4[b * F4 + k * 16 + dd];

        float s[APB];
#pragma unroll
        for (int j = 0; j < APB; ++j) {
            float sx = 0.f, sy = 0.f, sz = 0.f, sw = 0.f;
#pragma unroll
            for (int k = 0; k < 4; ++k) {
                float dx = row[k].x - xa[j][k].x;
                float dy = row[k].y - xa[j][k].y;
                float dz = row[k].z - xa[j][k].z;
                float dw = row[k].w - xa[j][k].w;
                sx += dx * dx;
                sy += dy * dy;
                sz += dz * dz;
                sw += dw * dw;
            }
            s[j] = (sx + sy) + (sz + sw);
        }
        // 16-lane butterfly (stays within the rr segment for masks 1,2,4,8)
#pragma unroll
        for (int mask = 1; mask < 16; mask <<= 1)
#pragma unroll
            for (int j = 0; j < APB; ++j)
                s[j] += __shfl_xor(s[j], mask, 64);

        if (dd == 0) s_d[0][b] = s[0];
        if (dd == 1) s_d[1][b] = s[1];
    }
    __syncthreads();

    // ---- triplet phase: anchors a0..a0+APB-1 sequentially ----
    for (int j = 0; j < APB; ++j) {
        const int a = a0 + j;
        if (tid == 0) { s_np = 0; s_cnt = 0; }
        __syncthreads();

        const int la = s_lab[a];
        for (int i = tid; i < BB; i += 256) {
            if (s_lab[i] == la) {
                atomicAdd(&s_cnt, 1);
                if (i > a) {
                    int k = atomicAdd(&s_np, 1);
                    s_pos[k] = i;
                }
            }
        }
        __syncthreads();

        const int np = s_np;
        const int cnt = s_cnt;

        double num_local = 0.0;
        for (int pi = 0; pi < np; ++pi) {
            const float t = MARGIN + s_d[j][s_pos[pi]];
            for (int n = tid; n < BB; n += 256) {
                if (s_lab[n] != la) {
                    float l = t - s_d[j][n];
                    if (l > 0.f) num_local += (double)l;
                }
            }
        }

        for (int off = 32; off > 0; off >>= 1)
            num_local += __shfl_down(num_local, off, 64);
        if (lane == 0) s_red[wave] = num_local;
        __syncthreads();

        if (tid == 0) {
            double tot = (s_red[0] + s_red[1]) + (s_red[2] + s_red[3]);
            partial_num[a] = tot * (double)cnt;
            partial_den[a] = (double)cnt * (double)np * (double)(BB - cnt);
        }
        __syncthreads();  // protect s_np/s_cnt/s_red reuse in next j
    }
}

// ---------------------------------------------------------------------------
// Finalize: reduce 384 partial num/den pairs, emit num/den.
// ---------------------------------------------------------------------------
__global__ __launch_bounds__(256) void finalize_kernel(
    const double* __restrict__ partial_num,
    const double* __restrict__ partial_den,
    float* __restrict__ out) {
    __shared__ double s_red[8];
    const int tid = threadIdx.x;

    double n_local = 0.0, d_local = 0.0;
    for (int i = tid; i < BB; i += 256) {
        n_local += partial_num[i];
        d_local += partial_den[i];
    }
    for (int off = 32; off > 0; off >>= 1) {
        n_local += __shfl_down(n_local, off, 64);
        d_local += __shfl_down(d_local, off, 64);
    }
    const int lane = tid & 63, wid = tid >> 6;
    if (lane == 0) { s_red[wid] = n_local; s_red[4 + wid] = d_local; }
    __syncthreads();

    if (tid == 0) {
        double num = (s_red[0] + s_red[1]) + (s_red[2] + s_red[3]);
        double den = (s_red[4] + s_red[5]) + (s_red[6] + s_red[7]);
        out[0] = (den > 0.0) ? (float)(num / den) : 0.0f;
    }
}

extern "C" void kernel_launch(void* const* d_in, const int* in_sizes, int n_in,
                              void* d_out, int out_size, void* d_ws, size_t ws_size,
                              hipStream_t stream) {
    const float* x = (const float*)d_in[0];
    const int* labels = (const int*)d_in[1];
    float* out = (float*)d_out;

    double* partial_num = (double*)d_ws;
    double* partial_den = partial_num + BB;

    triplet_fused_kernel<<<NBLK, 256, 0, stream>>>(x, labels, partial_num, partial_den);
    finalize_kernel<<<1, 256, 0, stream>>>(partial_num, partial_den, out);
}